// Round 8
// baseline (128.685 us; speedup 1.0000x reference)
//
#include <hip/hip_runtime.h>
#include <hip/hip_bf16.h>

#define BLOCK    256
#define RT       4          // row-tiles (16 rows each) per wave -> 64 rows/wave
#define ROWS_PB  256        // rows per block (4 waves x 64)
#define DCH      16         // col splits; cols per block = 16384/16 = 1024
#define NPTS     16384

typedef __attribute__((ext_vector_type(8)))  short s16x8;   // 8 bf16 = MFMA A/B frag
typedef __attribute__((ext_vector_type(4)))  float f32x4;   // MFMA C/D frag

__device__ inline unsigned short bf16_rtn(float v) {
    __hip_bfloat16 h = __float2bfloat16(v);
    return __builtin_bit_cast(unsigned short, h);
}
__device__ inline float bf16_back(unsigned short u) {
    return __bfloat162float(__builtin_bit_cast(__hip_bfloat16, u));
}

// Build MFMA fragment streams in exact lane order.
// A (from Xc, scaled by -2): K-vector per row i:
//   k0..7  = [xh,xh,xl,yh,yh,yl,zh,zh]   (quad 0)
//   k8..10 = [zl, 1, 1]                  (quad 1), rest 0
// B (from Xt, unscaled, + |p|^2 hi/lo): per col j:
//   k0..7  = [xh,xl,xh,yh,yl,yh,zh,zl]
//   k8..10 = [zh, p2h, p2l], rest 0
// Dot over k = -2 q.p + p2  (bf16x3: drops only lo*lo terms, ~2^-17 rel).
__global__ __launch_bounds__(BLOCK) void chamfer_prep(
    const float* __restrict__ Xc, const float* __restrict__ Xt,
    s16x8* __restrict__ Astream, s16x8* __restrict__ Bstream,
    float* __restrict__ q2c,
    unsigned* __restrict__ minQ, unsigned* __restrict__ minDb,
    float* __restrict__ out)
{
    int tid  = blockIdx.x * BLOCK + threadIdx.x;   // 0 .. 1024*64-1
    int lane = tid & 63;
    int rt   = tid >> 6;        // tile index 0..1023
    int quad = lane >> 4;
    int mcol = lane & 15;
    int i    = rt * 16 + mcol;  // point index this lane serves

    if (tid == 0) out[0] = 0.0f;
    if (tid < NPTS) {
        float x = Xc[tid * 3 + 0], y = Xc[tid * 3 + 1], z = Xc[tid * 3 + 2];
        q2c[tid]   = x * x + y * y + z * z;
        minQ[tid]  = 0xFFFFFFFFu;
        minDb[tid] = 0xFFFFFFFFu;
    }

    const unsigned short ONE = 0x3F80;  // bf16(1.0)

    // ---- A fragment (Xc, -2 scale) ----
    {
        float x = -2.0f * Xc[i * 3 + 0];
        float y = -2.0f * Xc[i * 3 + 1];
        float z = -2.0f * Xc[i * 3 + 2];
        unsigned short xh = bf16_rtn(x), xl = bf16_rtn(x - bf16_back(xh));
        unsigned short yh = bf16_rtn(y), yl = bf16_rtn(y - bf16_back(yh));
        unsigned short zh = bf16_rtn(z), zl = bf16_rtn(z - bf16_back(zh));
        s16x8 a = (s16x8){0,0,0,0,0,0,0,0};
        if (quad == 0) a = (s16x8){(short)xh,(short)xh,(short)xl,(short)yh,
                                   (short)yh,(short)yl,(short)zh,(short)zh};
        if (quad == 1) a = (s16x8){(short)zl,(short)ONE,(short)ONE,0,0,0,0,0};
        Astream[tid] = a;
    }
    // ---- B fragment (Xt, + p2 split) ----
    {
        float x = Xt[i * 3 + 0], y = Xt[i * 3 + 1], z = Xt[i * 3 + 2];
        float p2 = x * x + y * y + z * z;
        unsigned short xh = bf16_rtn(x), xl = bf16_rtn(x - bf16_back(xh));
        unsigned short yh = bf16_rtn(y), yl = bf16_rtn(y - bf16_back(yh));
        unsigned short zh = bf16_rtn(z), zl = bf16_rtn(z - bf16_back(zh));
        unsigned short ph = bf16_rtn(p2), pl = bf16_rtn(p2 - bf16_back(ph));
        s16x8 b = (s16x8){0,0,0,0,0,0,0,0};
        if (quad == 0) b = (s16x8){(short)xh,(short)xl,(short)xh,(short)yh,
                                   (short)yl,(short)yh,(short)zh,(short)zl};
        if (quad == 1) b = (s16x8){(short)zh,(short)ph,(short)pl,0,0,0,0,0};
        Bstream[tid] = b;
    }
}

// One Gram pass serves BOTH chamfer directions. Wave holds RT A-frags
// (resident), streams B-frags from global (L2-resident, coalesced 16B/lane),
// one mfma_f32_16x16x32_bf16 per 16x16 tile. C/D layout: col=lane&15,
// row=quad*4+reg (m89-verified). rowmin accumulated in registers, flushed
// once; colmin flushed per col-tile via 2 shfl_xor + 16 atomics.
__global__ __launch_bounds__(BLOCK, 4) void chamfer_gram(
    const s16x8* __restrict__ Astream, const s16x8* __restrict__ Bstream,
    const float* __restrict__ q2c,
    unsigned* __restrict__ minQ, unsigned* __restrict__ minDb)
{
    const int lane = threadIdx.x & 63;
    const int wave = threadIdx.x >> 6;
    const int quad = lane >> 4;

    const int rowTile0 = blockIdx.x * (ROWS_PB / 16) + wave * RT; // global row-tile
    const int colTile0 = blockIdx.y * (NPTS / DCH / 16);          // 64 col-tiles/block
    const int nColT    = NPTS / DCH / 16;

    // Resident A-frags + per-row q2 (float4 per row-tile: rows quad*4+reg)
    s16x8 afrag[RT];
    f32x4 q2r[RT];
    f32x4 rowmin[RT];
#pragma unroll
    for (int r = 0; r < RT; ++r) {
        afrag[r]  = Astream[(rowTile0 + r) * 64 + lane];
        q2r[r]    = *(const f32x4*)&q2c[(rowTile0 + r) * 16 + quad * 4];
        rowmin[r] = (f32x4){3.4e38f, 3.4e38f, 3.4e38f, 3.4e38f};
    }

    const s16x8* Bp = Bstream + (size_t)colTile0 * 64 + lane;

    for (int t = 0; t < nColT; ++t) {
        s16x8 b = Bp[t * 64];

        f32x4 g[RT];
#pragma unroll
        for (int r = 0; r < RT; ++r)
            g[r] = __builtin_amdgcn_mfma_f32_16x16x32_bf16(
                       afrag[r], b, (f32x4){0.f, 0.f, 0.f, 0.f}, 0, 0, 0);

        float cmin = 3.4e38f;
#pragma unroll
        for (int r = 0; r < RT; ++r) {
            // row direction: g already includes +p2 fold
            rowmin[r] = __builtin_elementwise_min(rowmin[r], g[r]);
            // col direction: add q2 per row, min across the 4 rows
            f32x4 tq = g[r] + q2r[r];
            cmin = fminf(fminf(tq.x, tq.y), fminf(fminf(tq.z, tq.w), cmin));
        }
        // reduce over quads (rows 0..15 of this tile live in 4 lane-groups)
        cmin = fminf(cmin, __shfl_xor(cmin, 16));
        cmin = fminf(cmin, __shfl_xor(cmin, 32));
        if (lane < 16)
            atomicMin(&minDb[colTile0 * 16 + t * 16 + lane],
                      __float_as_uint(fmaxf(cmin, 0.0f)));
    }

    // Flush rowmin: reduce across the 16 cols (lane&15), then one atomic/row.
#pragma unroll
    for (int r = 0; r < RT; ++r) {
#pragma unroll
        for (int xm = 1; xm <= 8; xm <<= 1) {
            rowmin[r].x = fminf(rowmin[r].x, __shfl_xor(rowmin[r].x, xm));
            rowmin[r].y = fminf(rowmin[r].y, __shfl_xor(rowmin[r].y, xm));
            rowmin[r].z = fminf(rowmin[r].z, __shfl_xor(rowmin[r].z, xm));
            rowmin[r].w = fminf(rowmin[r].w, __shfl_xor(rowmin[r].w, xm));
        }
        if ((lane & 15) == 0) {
            f32x4 d = rowmin[r] + q2r[r];
            int rowb = (rowTile0 + r) * 16 + quad * 4;
            atomicMin(&minQ[rowb + 0], __float_as_uint(fmaxf(d.x, 0.0f)));
            atomicMin(&minQ[rowb + 1], __float_as_uint(fmaxf(d.y, 0.0f)));
            atomicMin(&minQ[rowb + 2], __float_as_uint(fmaxf(d.z, 0.0f)));
            atomicMin(&minQ[rowb + 3], __float_as_uint(fmaxf(d.w, 0.0f)));
        }
    }
}

// Multi-block reduce: block partial sums -> one atomicAdd per block.
#define RBLOCKS 128
__global__ __launch_bounds__(BLOCK) void chamfer_reduce(
    const unsigned* __restrict__ minQ, const unsigned* __restrict__ minDb,
    float* __restrict__ out, int n, int m)
{
    __shared__ float red[4];
    float s = 0.0f;
    const float invn = 1.0f / (float)n, invm = 1.0f / (float)m;
    for (int i = blockIdx.x * BLOCK + threadIdx.x; i < n; i += RBLOCKS * BLOCK)
        s += __uint_as_float(minQ[i]) * invn;
    for (int i = blockIdx.x * BLOCK + threadIdx.x; i < m; i += RBLOCKS * BLOCK)
        s += __uint_as_float(minDb[i]) * invm;

#pragma unroll
    for (int off = 32; off > 0; off >>= 1) s += __shfl_down(s, off, 64);
    int wave = threadIdx.x >> 6;
    int lane = threadIdx.x & 63;
    if (lane == 0) red[wave] = s;
    __syncthreads();
    if (threadIdx.x == 0) {
        float t = red[0] + red[1] + red[2] + red[3];
        atomicAdd(out, t);
    }
}

extern "C" void kernel_launch(void* const* d_in, const int* in_sizes, int n_in,
                              void* d_out, int out_size, void* d_ws, size_t ws_size,
                              hipStream_t stream) {
    const float* Xc = (const float*)d_in[0];
    const float* Xt = (const float*)d_in[1];
    const int n = in_sizes[0] / 3;   // 16384
    const int m = in_sizes[1] / 3;   // 16384

    // ws: minQ[n] | minDb[m] | q2c[n] f32 | Astream 1MB | Bstream 1MB
    unsigned* minQ  = (unsigned*)d_ws;
    unsigned* minDb = minQ + n;
    float*    q2c   = (float*)(minDb + m);
    s16x8*    As    = (s16x8*)(q2c + n);
    s16x8*    Bs    = As + (size_t)(NPTS / 16) * 64;
    float*    out   = (float*)d_out;

    chamfer_prep<<<(NPTS / 16) * 64 / BLOCK, BLOCK, 0, stream>>>(
        Xc, Xt, As, Bs, q2c, minQ, minDb, out);

    dim3 grid(NPTS / ROWS_PB, DCH);   // 64 x 16 = 1024 blocks
    chamfer_gram<<<grid, BLOCK, 0, stream>>>(As, Bs, q2c, minQ, minDb);

    chamfer_reduce<<<RBLOCKS, BLOCK, 0, stream>>>(minQ, minDb, out, n, m);
}